// Round 7
// baseline (612.422 us; speedup 1.0000x reference)
//
#include <hip/hip_runtime.h>
#include <hip/hip_bf16.h>
#include <stdint.h>

#define NB 16
#define NPT 2048
#define NS 512
#define NK 32
#define PTOT (NB*NS*NK)   // 262144 positions
#define C_IN 67
#define EPSV 1e-5f

typedef __attribute__((ext_vector_type(8))) short short8;
typedef __attribute__((ext_vector_type(4))) float floatx4;

// ws layout (float indices) — FIXED: bf16 sizes are elems/2 floats, not /4
#define WS_NEWXYZ 0            // 24576
#define WS_GIDX   24576        // ints -> 286720
#define WS_PART1  286720       // 64 blocks x 128 = 8192 -> 294912
#define WS_PART2  294912       // 8192 -> 303104
#define WS_PART3  303104       // 128 blocks x 256 = 32768 -> 335872
#define WS_AFF    335872       // 512 -> 336384
#define WS_W1BF   336384       // 4096 bf16 = 2048 -> 338432
#define WS_W2BF   338432       // 8192 bf16 = 4096 -> 342528
#define WS_RAWMAX 342528       // 1048576 bf16 = 524288 -> 866816
#define WS_PTS_T  866816       // 2097152 -> 2963968
#define WS_Y1     2963968      // 64*PTOT bf16 = 8388608 floats -> 11352576
#define WS_Y2     11352576     // 8388608 -> 19741184
#define WS_Y3     19741184     // 128*PTOT bf16 = 16777216 floats -> 36518400 (~146MB)

__device__ __forceinline__ float bf2f(ushort u){ return __uint_as_float((uint32_t)u<<16); }
__device__ __forceinline__ ushort f2bf(float f){
  uint32_t u = __float_as_uint(f);
  return (ushort)((u + 0x7FFFu + ((u>>16)&1u)) >> 16);
}

// ---- DPP 64-bit max step on a positive-double key ----
template<int CTRL>
__device__ __forceinline__ double dppmax64f(double k){
  long long b = __double_as_longlong(k);
  int lo = (int)(uint32_t)b, hi = (int)(b>>32);
  int olo = __builtin_amdgcn_update_dpp(lo, lo, CTRL, 0xF, 0xF, false);
  int ohi = __builtin_amdgcn_update_dpp(hi, hi, CTRL, 0xF, 0xF, false);
  double o = __hiloint2double(ohi, olo);
  return fmax(o, k);
}
__device__ __forceinline__ unsigned long long u64max(unsigned long long a, unsigned long long b){ return a>b?a:b; }

// ---------------- FPS (round-3 version, measured ~222us) ----------------
__global__ __launch_bounds__(256) void fps_kernel(const float* __restrict__ xyz,
                                                  float* __restrict__ nxyz,
                                                  float* __restrict__ out0)
{
  __shared__ float4 lc[NPT];
  __shared__ double warr[2][4];
  __shared__ int sel[NS];
  const int b = blockIdx.x;
  const int tid = threadIdx.x;
  const float* xb = xyz + (size_t)b*3*NPT;
  float px[8], py[8], pz[8], dist[8];
  uint32_t lo_[8];
  #pragma unroll
  for (int j=0;j<8;j++){
    int n = j*256 + tid;
    float x = xb[n], y = xb[NPT+n], z = xb[2*NPT+n];
    lc[n] = make_float4(x,y,z,0.f);
    px[j]=x; py[j]=y; pz[j]=z; dist[j]=1e10f;
    lo_[j] = ~(uint32_t)n;
  }
  if (tid==0) sel[0]=0;
  __syncthreads();
  float4 c0 = lc[0];
  float cx = c0.x, cy = c0.y, cz = c0.z;
  const int lane = tid & 63, wid = tid >> 6;
  for (int t=1;t<NS;t++){
    double kk[8];
    #pragma unroll
    for (int j=0;j<8;j++){
      float dx = __fsub_rn(px[j], cx);
      float dy = __fsub_rn(py[j], cy);
      float dz = __fsub_rn(pz[j], cz);
      float d  = __fadd_rn(__fadd_rn(__fmul_rn(dx,dx),__fmul_rn(dy,dy)),__fmul_rn(dz,dz));
      float dd = fminf(dist[j], d);
      dist[j] = dd;
      kk[j] = __hiloint2double((int)__float_as_uint(dd), (int)lo_[j]);
    }
    double m0 = fmax(kk[0],kk[1]), m1 = fmax(kk[2],kk[3]);
    double m2 = fmax(kk[4],kk[5]), m3 = fmax(kk[6],kk[7]);
    double best = fmax(fmax(m0,m1), fmax(m2,m3));
    best = dppmax64f<0xB1>(best);
    best = dppmax64f<0x4E>(best);
    best = dppmax64f<0x124>(best);
    best = dppmax64f<0x128>(best);
    long long bb = __double_as_longlong(best);
    int bl = (int)(uint32_t)bb, bh = (int)(bb>>32);
    unsigned long long k0 = (((unsigned long long)(uint32_t)__builtin_amdgcn_readlane(bh, 0))<<32)  | (uint32_t)__builtin_amdgcn_readlane(bl, 0);
    unsigned long long k1 = (((unsigned long long)(uint32_t)__builtin_amdgcn_readlane(bh, 16))<<32) | (uint32_t)__builtin_amdgcn_readlane(bl, 16);
    unsigned long long k2 = (((unsigned long long)(uint32_t)__builtin_amdgcn_readlane(bh, 32))<<32) | (uint32_t)__builtin_amdgcn_readlane(bl, 32);
    unsigned long long k3 = (((unsigned long long)(uint32_t)__builtin_amdgcn_readlane(bh, 48))<<32) | (uint32_t)__builtin_amdgcn_readlane(bl, 48);
    unsigned long long kw = u64max(u64max(k0,k1), u64max(k2,k3));
    if (lane==0) warr[t&1][wid] = __longlong_as_double((long long)kw);
    __syncthreads();
    double w0 = warr[t&1][0], w1 = warr[t&1][1], w2 = warr[t&1][2], w3 = warr[t&1][3];
    double f = fmax(fmax(w0,w1), fmax(w2,w3));
    int n = (int)(~(uint32_t)__double_as_longlong(f));
    float4 cc = lc[n];
    cx = cc.x; cy = cc.y; cz = cc.z;
    if (tid==0) sel[t]=n;
  }
  __syncthreads();
  for (int s = tid; s < NS; s += 256){
    int n = sel[s];
    float4 cc = lc[n];
    float* np_ = nxyz + ((size_t)b*NS + s)*3;
    np_[0]=cc.x; np_[1]=cc.y; np_[2]=cc.z;
    float* ob = out0 + (size_t)b*3*NS + s;
    ob[0]=cc.x; ob[NS]=cc.y; ob[2*NS]=cc.z;
  }
}

// ---------------- ball query ----------------
__global__ __launch_bounds__(256) void ballq_kernel(const float* __restrict__ xyz,
                                                    const float* __restrict__ nxyz,
                                                    int* __restrict__ gidx)
{
  const int g = blockIdx.x*4 + (threadIdx.x>>6);
  const int lane = threadIdx.x & 63;
  const int b = g >> 9;
  const float* xb = xyz + (size_t)b*3*NPT;
  const float* c = nxyz + (size_t)g*3;
  const float cx = c[0], cy = c[1], cz = c[2];
  const float r2 = 0.2f*0.2f;
  int cnt = 0; int first = 0;
  int* out = gidx + (size_t)g*NK;
  for (int ch=0; ch<NPT/64 && cnt<NK; ch++){
    int n = ch*64 + lane;
    float dx = __fsub_rn(cx, xb[n]);
    float dy = __fsub_rn(cy, xb[NPT+n]);
    float dz = __fsub_rn(cz, xb[2*NPT+n]);
    float d  = __fadd_rn(__fadd_rn(__fmul_rn(dx,dx),__fmul_rn(dy,dy)),__fmul_rn(dz,dz));
    bool in = (d <= r2);
    unsigned long long mask = __ballot(in);
    if (mask){
      if (cnt==0) first = ch*64 + (__ffsll((unsigned long long)mask)-1);
      if (in){
        int pos = cnt + __popcll(mask & ((1ull<<lane)-1ull));
        if (pos < NK) out[pos] = n;
      }
      cnt += __popcll(mask);
    }
  }
  if (cnt < NK && lane >= cnt && lane < NK) out[lane] = first;
}

// ---------------- transpose points (B,64,N) -> (B,N,64) fp32 ----------------
__global__ __launch_bounds__(256) void transpose_kernel(const float* __restrict__ pts,
                                                        float* __restrict__ pts_t)
{
  __shared__ float tile[64][65];
  const int blk = blockIdx.x;
  const int b = blk >> 5;
  const int n0 = (blk & 31) * 64;
  const int lane = threadIdx.x & 63;
  const int row4 = threadIdx.x >> 6;
  const float* src = pts + (size_t)b*64*NPT;
  #pragma unroll
  for (int r=0; r<16; r++){
    int cc = r*4 + row4;
    tile[cc][lane] = src[(size_t)cc*NPT + n0 + lane];
  }
  __syncthreads();
  float* dst = pts_t + ((size_t)b*NPT + n0)*64;
  #pragma unroll
  for (int r=0; r<16; r++){
    int nn = r*4 + row4;
    dst[(size_t)nn*64 + lane] = tile[lane][nn];
  }
}

// ---------------- weight fp32 -> bf16 ----------------
__global__ void wcvt_kernel(const float* __restrict__ w1, const float* __restrict__ w2,
                            ushort* __restrict__ w1b, ushort* __restrict__ w2b)
{
  int i = blockIdx.x*256 + threadIdx.x;
  if (i < 4096) w1b[i] = f2bf(w1[i]);
  else if (i < 12288) w2b[i-4096] = f2bf(w2[i-4096]);
}

// ---------------- conv1: gather + 67->64, position-major bf16 out ----------------
__global__ __launch_bounds__(256) void conv1_kernel(const float* __restrict__ xyz,
    const float* __restrict__ pts_t, const int* __restrict__ gidx,
    const float* __restrict__ nxyz, const float* __restrict__ Wt,
    const float* __restrict__ bias, ushort* __restrict__ y1)
{
  const int p = blockIdx.x*256 + threadIdx.x;
  const int bs = p >> 5;
  const int b = p >> 14;
  const int n = gidx[p];
  float x[C_IN];
  {
    const float* xb = xyz + (size_t)b*3*NPT;
    const float* cc = nxyz + (size_t)bs*3;
    x[0] = xb[n]        - cc[0];
    x[1] = xb[NPT+n]    - cc[1];
    x[2] = xb[2*NPT+n]  - cc[2];
    const float4* pr = (const float4*)(pts_t + ((size_t)b*NPT + n)*64);
    #pragma unroll
    for (int q=0;q<16;q++){
      float4 v = pr[q];
      x[3+4*q]=v.x; x[4+4*q]=v.y; x[5+4*q]=v.z; x[6+4*q]=v.w;
    }
  }
  ushort* yr = y1 + (size_t)p*64;
  #pragma unroll 1
  for (int o=0;o<64;o+=8){
    float a[8];
    #pragma unroll
    for (int k=0;k<8;k++) a[k] = bias[o+k];
    #pragma unroll
    for (int c=0;c<C_IN;c++){
      float xv = x[c];
      #pragma unroll
      for (int k=0;k<8;k++) a[k] = fmaf(Wt[(o+k)*C_IN+c], xv, a[k]);
    }
    short8 sv;
    #pragma unroll
    for (int k=0;k<8;k++) sv[k] = (short)f2bf(a[k]);
    *(short8*)(yr + o) = sv;
  }
}

// ---------------- stats over 64-ch position-major bf16: block partials ----------------
__global__ __launch_bounds__(256) void stats64_kernel(const ushort* __restrict__ y,
                                                      float* __restrict__ part)
{
  const int wid = threadIdx.x>>6, lane = threadIdx.x&63;
  const int oct = lane & 7, pr = lane >> 3;
  const int p0 = (blockIdx.x*4 + wid) * 1024;
  float s[8], s2[8];
  #pragma unroll
  for (int j=0;j<8;j++){ s[j]=0.f; s2[j]=0.f; }
  for (int it=0; it<128; it++){
    int p = p0 + it*8 + pr;
    short8 v = *(const short8*)(y + (size_t)p*64 + oct*8);
    #pragma unroll
    for (int j=0;j<8;j++){
      float f = bf2f((ushort)v[j]);
      s[j] += f; s2[j] = fmaf(f,f,s2[j]);
    }
  }
  #pragma unroll
  for (int off=8; off<64; off<<=1){
    #pragma unroll
    for (int j=0;j<8;j++){ s[j] += __shfl_xor(s[j],off,64); s2[j] += __shfl_xor(s2[j],off,64); }
  }
  __shared__ float sd[4][128];
  if (pr==0){
    #pragma unroll
    for (int j=0;j<8;j++){ sd[wid][oct*8+j] = s[j]; sd[wid][64+oct*8+j] = s2[j]; }
  }
  __syncthreads();
  int t = threadIdx.x;
  if (t < 128) part[(size_t)blockIdx.x*128 + t] = sd[0][t]+sd[1][t]+sd[2][t]+sd[3][t];
}

// ---------------- affine from partials ----------------
__global__ void affine_kernel(const float* __restrict__ part, int nrep, int C,
                              const float* __restrict__ g, const float* __restrict__ bt,
                              float* __restrict__ aA, float* __restrict__ aB)
{
  int c = threadIdx.x;
  if (c < C){
    float s=0.f, q=0.f;
    for (int r=0;r<nrep;r++){ s += part[(size_t)r*2*C + c]; q += part[(size_t)r*2*C + C + c]; }
    float mean = s * (1.f/PTOT);
    float var  = q * (1.f/PTOT) - mean*mean;
    float a = g[c] * rsqrtf(var + EPSV);
    aA[c] = a;
    aB[c] = fmaf(-mean, a, bt[c]);
  }
}

// ---------------- conv2 MFMA: 64->64, pm-bf16 in/out ----------------
__global__ __launch_bounds__(256) void conv2_mfma(const ushort* __restrict__ yin,
    const float* __restrict__ affA, const float* __restrict__ affB,
    const ushort* __restrict__ Wb, const float* __restrict__ bias,
    ushort* __restrict__ yout)
{
  const int wid = threadIdx.x>>6, lane = threadIdx.x&63;
  const int q = lane>>4, nn = lane&15;
  const int p0 = (blockIdx.x*4 + wid) * 32;
  float a_[2][8], b_[2][8];
  #pragma unroll
  for (int kh=0;kh<2;kh++)
    #pragma unroll
    for (int j=0;j<8;j++){
      a_[kh][j] = affA[kh*32 + q*8 + j];
      b_[kh][j] = affB[kh*32 + q*8 + j];
    }
  short8 Af[4][2];
  #pragma unroll
  for (int mt=0;mt<4;mt++)
    #pragma unroll
    for (int kh=0;kh<2;kh++)
      Af[mt][kh] = *(const short8*)(Wb + (mt*16 + nn)*64 + kh*32 + q*8);
  float bias_[4][4];
  #pragma unroll
  for (int mt=0;mt<4;mt++)
    #pragma unroll
    for (int r=0;r<4;r++) bias_[mt][r] = bias[mt*16 + q*4 + r];
  floatx4 z = {0.f,0.f,0.f,0.f};
  floatx4 acc[4][2];
  #pragma unroll
  for (int mt=0;mt<4;mt++){ acc[mt][0]=z; acc[mt][1]=z; }
  #pragma unroll
  for (int nt=0;nt<2;nt++){
    #pragma unroll
    for (int kh=0;kh<2;kh++){
      short8 raw = *(const short8*)(yin + (size_t)(p0 + nt*16 + nn)*64 + kh*32 + q*8);
      short8 bf;
      #pragma unroll
      for (int j=0;j<8;j++){
        float f = bf2f((ushort)raw[j]);
        f = fmaxf(fmaf(f, a_[kh][j], b_[kh][j]), 0.f);
        bf[j] = (short)f2bf(f);
      }
      #pragma unroll
      for (int mt=0;mt<4;mt++)
        acc[mt][nt] = __builtin_amdgcn_mfma_f32_16x16x32_bf16(Af[mt][kh], bf, acc[mt][nt], 0,0,0);
    }
  }
  #pragma unroll
  for (int nt=0;nt<2;nt++){
    int p = p0 + nt*16 + nn;
    #pragma unroll
    for (int mt=0;mt<4;mt++){
      float v0 = acc[mt][nt][0] + bias_[mt][0];
      float v1 = acc[mt][nt][1] + bias_[mt][1];
      float v2 = acc[mt][nt][2] + bias_[mt][2];
      float v3 = acc[mt][nt][3] + bias_[mt][3];
      uint2 w;
      w.x = (uint32_t)f2bf(v0) | ((uint32_t)f2bf(v1)<<16);
      w.y = (uint32_t)f2bf(v2) | ((uint32_t)f2bf(v3)<<16);
      *(uint2*)(yout + (size_t)p*64 + mt*16 + q*4) = w;
    }
  }
}

// ---------------- conv3 MFMA: 64->128, pm-bf16 in/out ----------------
__global__ __launch_bounds__(256) void conv3_mfma(const ushort* __restrict__ yin,
    const float* __restrict__ affA, const float* __restrict__ affB,
    const ushort* __restrict__ Wb, const float* __restrict__ bias,
    ushort* __restrict__ yout)
{
  const int wid = threadIdx.x>>6, lane = threadIdx.x&63;
  const int q = lane>>4, nn = lane&15;
  const int p0 = (blockIdx.x*4 + wid) * 16;
  float a_[2][8], b_[2][8];
  #pragma unroll
  for (int kh=0;kh<2;kh++)
    #pragma unroll
    for (int j=0;j<8;j++){
      a_[kh][j] = affA[kh*32 + q*8 + j];
      b_[kh][j] = affB[kh*32 + q*8 + j];
    }
  short8 bfr[2];
  #pragma unroll
  for (int kh=0;kh<2;kh++){
    short8 raw = *(const short8*)(yin + (size_t)(p0 + nn)*64 + kh*32 + q*8);
    short8 bf;
    #pragma unroll
    for (int j=0;j<8;j++){
      float f = bf2f((ushort)raw[j]);
      f = fmaxf(fmaf(f, a_[kh][j], b_[kh][j]), 0.f);
      bf[j] = (short)f2bf(f);
    }
    bfr[kh] = bf;
  }
  #pragma unroll 1
  for (int mh=0;mh<2;mh++){
    floatx4 z = {0.f,0.f,0.f,0.f};
    floatx4 acc[4];
    short8 Af[4][2];
    #pragma unroll
    for (int mt=0;mt<4;mt++){
      acc[mt]=z;
      #pragma unroll
      for (int kh=0;kh<2;kh++)
        Af[mt][kh] = *(const short8*)(Wb + ((mh*4+mt)*16 + nn)*64 + kh*32 + q*8);
    }
    #pragma unroll
    for (int kh=0;kh<2;kh++)
      #pragma unroll
      for (int mt=0;mt<4;mt++)
        acc[mt] = __builtin_amdgcn_mfma_f32_16x16x32_bf16(Af[mt][kh], bfr[kh], acc[mt], 0,0,0);
    int p = p0 + nn;
    #pragma unroll
    for (int mt=0;mt<4;mt++){
      int m0 = (mh*4+mt)*16;
      float v0 = acc[mt][0] + bias[m0 + q*4 + 0];
      float v1 = acc[mt][1] + bias[m0 + q*4 + 1];
      float v2 = acc[mt][2] + bias[m0 + q*4 + 2];
      float v3 = acc[mt][3] + bias[m0 + q*4 + 3];
      uint2 w;
      w.x = (uint32_t)f2bf(v0) | ((uint32_t)f2bf(v1)<<16);
      w.y = (uint32_t)f2bf(v2) | ((uint32_t)f2bf(v3)<<16);
      *(uint2*)(yout + (size_t)p*128 + m0 + q*4) = w;
    }
  }
}

// ---------------- stats + group-max over 128-ch pm-bf16 y3 ----------------
__global__ __launch_bounds__(256) void statsmax_kernel(const ushort* __restrict__ y,
    float* __restrict__ part, ushort* __restrict__ rawmax)
{
  const int wid = threadIdx.x>>6, lane = threadIdx.x&63;
  const int oct = lane & 15, pr = lane >> 4;
  const int g0 = (blockIdx.x*4 + wid) * 16;
  float s[8], s2[8];
  #pragma unroll
  for (int j=0;j<8;j++){ s[j]=0.f; s2[j]=0.f; }
  for (int gi=0; gi<16; gi++){
    int g = g0 + gi;
    float mx[8];
    #pragma unroll
    for (int j=0;j<8;j++) mx[j] = -1e30f;
    for (int it=0; it<8; it++){
      int p = g*32 + it*4 + pr;
      short8 v = *(const short8*)(y + (size_t)p*128 + oct*8);
      #pragma unroll
      for (int j=0;j<8;j++){
        float f = bf2f((ushort)v[j]);
        s[j] += f; s2[j] = fmaf(f,f,s2[j]);
        mx[j] = fmaxf(mx[j], f);
      }
    }
    #pragma unroll
    for (int j=0;j<8;j++){
      mx[j] = fmaxf(mx[j], __shfl_xor(mx[j],16,64));
      mx[j] = fmaxf(mx[j], __shfl_xor(mx[j],32,64));
    }
    if (pr==0){
      short8 sv;
      #pragma unroll
      for (int j=0;j<8;j++) sv[j] = (short)f2bf(mx[j]);
      *(short8*)(rawmax + (size_t)g*128 + oct*8) = sv;
    }
  }
  #pragma unroll
  for (int j=0;j<8;j++){
    s[j]  += __shfl_xor(s[j],16,64);  s[j]  += __shfl_xor(s[j],32,64);
    s2[j] += __shfl_xor(s2[j],16,64); s2[j] += __shfl_xor(s2[j],32,64);
  }
  __shared__ float sd[4][256];
  if (pr==0){
    #pragma unroll
    for (int j=0;j<8;j++){ sd[wid][oct*8+j] = s[j]; sd[wid][128+oct*8+j] = s2[j]; }
  }
  __syncthreads();
  int t = threadIdx.x;
  part[(size_t)blockIdx.x*256 + t] = sd[0][t]+sd[1][t]+sd[2][t]+sd[3][t];
}

// ---------------- finalize ----------------
__global__ __launch_bounds__(256) void finalize_kernel(const ushort* __restrict__ rawmax,
    const float* __restrict__ affA, const float* __restrict__ affB,
    float* __restrict__ out)
{
  int i = blockIdx.x*256 + threadIdx.x;  // (b*128+c)*512+s
  int c = (i >> 9) & 127, s = i & 511, b = i >> 16;
  float a = affA[c], bb = affB[c];
  float v = bf2f(rawmax[(size_t)(b*512+s)*128 + c]);
  out[i] = fmaxf(fmaf(v, a, bb), 0.f);
}

extern "C" void kernel_launch(void* const* d_in, const int* in_sizes, int n_in,
                              void* d_out, int out_size, void* d_ws, size_t ws_size,
                              hipStream_t stream) {
  const float* xyz = (const float*)d_in[0];
  const float* pts = (const float*)d_in[1];
  const float* w0  = (const float*)d_in[2];
  const float* b0  = (const float*)d_in[3];
  const float* g0  = (const float*)d_in[4];
  const float* bt0 = (const float*)d_in[5];
  const float* w1  = (const float*)d_in[6];
  const float* b1  = (const float*)d_in[7];
  const float* g1  = (const float*)d_in[8];
  const float* bt1 = (const float*)d_in[9];
  const float* w2  = (const float*)d_in[10];
  const float* b2  = (const float*)d_in[11];
  const float* g2  = (const float*)d_in[12];
  const float* bt2 = (const float*)d_in[13];
  float* out = (float*)d_out;
  float* ws  = (float*)d_ws;

  float* nxyz   = ws + WS_NEWXYZ;
  int*   gidx   = (int*)(ws + WS_GIDX);
  float* part1  = ws + WS_PART1;
  float* part2  = ws + WS_PART2;
  float* part3  = ws + WS_PART3;
  float *aA0 = ws+WS_AFF,     *aB0 = ws+WS_AFF+64;
  float *aA1 = ws+WS_AFF+128, *aB1 = ws+WS_AFF+192;
  float *aA2 = ws+WS_AFF+256, *aB2 = ws+WS_AFF+384;
  ushort* w1b = (ushort*)(ws + WS_W1BF);
  ushort* w2b = (ushort*)(ws + WS_W2BF);
  ushort* rawmax = (ushort*)(ws + WS_RAWMAX);
  float* pts_t  = ws + WS_PTS_T;
  ushort* y1 = (ushort*)(ws + WS_Y1);
  ushort* y2 = (ushort*)(ws + WS_Y2);
  ushort* y3 = (ushort*)(ws + WS_Y3);

  transpose_kernel<<<512,256,0,stream>>>(pts, pts_t);
  fps_kernel<<<NB,256,0,stream>>>(xyz, nxyz, out);
  ballq_kernel<<<2048,256,0,stream>>>(xyz, nxyz, gidx);
  wcvt_kernel<<<48,256,0,stream>>>(w1, w2, w1b, w2b);
  conv1_kernel<<<PTOT/256,256,0,stream>>>(xyz, pts_t, gidx, nxyz, w0, b0, y1);
  stats64_kernel<<<64,256,0,stream>>>(y1, part1);
  affine_kernel<<<1,64,0,stream>>>(part1, 64, 64, g0, bt0, aA0, aB0);
  conv2_mfma<<<2048,256,0,stream>>>(y1, aA0, aB0, w1b, b1, y2);
  stats64_kernel<<<64,256,0,stream>>>(y2, part2);
  affine_kernel<<<1,64,0,stream>>>(part2, 64, 64, g1, bt1, aA1, aB1);
  conv3_mfma<<<4096,256,0,stream>>>(y2, aA1, aB1, w2b, b2, y3);
  statsmax_kernel<<<128,256,0,stream>>>(y3, part3, rawmax);
  affine_kernel<<<1,128,0,stream>>>(part3, 128, 128, g2, bt2, aA2, aB2);
  finalize_kernel<<<4096,256,0,stream>>>(rawmax, aA2, aB2, out + NB*3*NS);
}

// Round 8
// 515.337 us; speedup vs baseline: 1.1884x; 1.1884x over previous
//
#include <hip/hip_runtime.h>
#include <hip/hip_bf16.h>
#include <stdint.h>

#define NB 16
#define NPT 2048
#define NS 512
#define NK 32
#define PTOT (NB*NS*NK)   // 262144 positions
#define C_IN 67
#define EPSV 1e-5f

typedef __attribute__((ext_vector_type(8))) short short8;
typedef __attribute__((ext_vector_type(4))) float floatx4;

// ws layout (float indices)
#define WS_NEWXYZ 0            // 24576
#define WS_GIDX   24576        // ints -> 286720
// ST: sum0 2x64@0, sq0 2x64@128, sum1 2x64@256, sq1 2x64@384, sum2 4x128@512, sq2 4x128@1024 -> 1536
#define WS_ST     286720       // -> 288256
#define WS_W1BF   288256       // 4096 bf16 -> 290304
#define WS_W2BF   290304       // 8192 bf16 -> 294400
#define WS_RAWMAX 294400       // 1048576 bf16 = 524288 fl -> 818688
#define WS_PTS_TB 818688       // B*N*64 bf16 = 1048576 fl -> 1867264
#define WS_Y1     1867264      // 64*PTOT bf16 = 8388608 fl -> 10255872
#define WS_Y2     10255872     // -> 18644480
#define WS_Y3     18644480     // 128*PTOT bf16 -> 35421696 (~142MB)

__device__ __forceinline__ float bf2f(ushort u){ return __uint_as_float((uint32_t)u<<16); }
__device__ __forceinline__ ushort f2bf(float f){
  uint32_t u = __float_as_uint(f);
  return (ushort)((u + 0x7FFFu + ((u>>16)&1u)) >> 16);
}

template<int CTRL>
__device__ __forceinline__ double dppmax64f(double k){
  long long b = __double_as_longlong(k);
  int lo = (int)(uint32_t)b, hi = (int)(b>>32);
  int olo = __builtin_amdgcn_update_dpp(lo, lo, CTRL, 0xF, 0xF, false);
  int ohi = __builtin_amdgcn_update_dpp(hi, hi, CTRL, 0xF, 0xF, false);
  double o = __hiloint2double(ohi, olo);
  return fmax(o, k);
}
__device__ __forceinline__ unsigned long long u64max(unsigned long long a, unsigned long long b){ return a>b?a:b; }

// ---------------- prep: fps (blocks 0-15) + transpose->bf16 (16-527) + wcvt/zero (528) ----------------
__global__ __launch_bounds__(256) void prep_kernel(const float* __restrict__ xyz,
    float* __restrict__ nxyz, float* __restrict__ out0,
    const float* __restrict__ pts, ushort* __restrict__ pts_tb,
    const float* __restrict__ w1, const float* __restrict__ w2,
    ushort* __restrict__ w1b, ushort* __restrict__ w2b, float* __restrict__ st)
{
  __shared__ union {
    struct { float4 lc[NPT]; double warr[2][4]; int sel[NS]; } f;
    float tile[64][65];
  } sm;
  const int blk = blockIdx.x;
  const int tid = threadIdx.x;
  if (blk < 16){
    // ---- FPS (round-3 body, measured ~222us) ----
    const int b = blk;
    const float* xb = xyz + (size_t)b*3*NPT;
    float px[8], py[8], pz[8], dist[8];
    uint32_t lo_[8];
    #pragma unroll
    for (int j=0;j<8;j++){
      int n = j*256 + tid;
      float x = xb[n], y = xb[NPT+n], z = xb[2*NPT+n];
      sm.f.lc[n] = make_float4(x,y,z,0.f);
      px[j]=x; py[j]=y; pz[j]=z; dist[j]=1e10f;
      lo_[j] = ~(uint32_t)n;
    }
    if (tid==0) sm.f.sel[0]=0;
    __syncthreads();
    float4 c0 = sm.f.lc[0];
    float cx = c0.x, cy = c0.y, cz = c0.z;
    const int lane = tid & 63, wid = tid >> 6;
    for (int t=1;t<NS;t++){
      double kk[8];
      #pragma unroll
      for (int j=0;j<8;j++){
        float dx = __fsub_rn(px[j], cx);
        float dy = __fsub_rn(py[j], cy);
        float dz = __fsub_rn(pz[j], cz);
        float d  = __fadd_rn(__fadd_rn(__fmul_rn(dx,dx),__fmul_rn(dy,dy)),__fmul_rn(dz,dz));
        float dd = fminf(dist[j], d);
        dist[j] = dd;
        kk[j] = __hiloint2double((int)__float_as_uint(dd), (int)lo_[j]);
      }
      double m0 = fmax(kk[0],kk[1]), m1 = fmax(kk[2],kk[3]);
      double m2 = fmax(kk[4],kk[5]), m3 = fmax(kk[6],kk[7]);
      double best = fmax(fmax(m0,m1), fmax(m2,m3));
      best = dppmax64f<0xB1>(best);
      best = dppmax64f<0x4E>(best);
      best = dppmax64f<0x124>(best);
      best = dppmax64f<0x128>(best);
      long long bb = __double_as_longlong(best);
      int bl = (int)(uint32_t)bb, bh = (int)(bb>>32);
      unsigned long long k0 = (((unsigned long long)(uint32_t)__builtin_amdgcn_readlane(bh, 0))<<32)  | (uint32_t)__builtin_amdgcn_readlane(bl, 0);
      unsigned long long k1 = (((unsigned long long)(uint32_t)__builtin_amdgcn_readlane(bh, 16))<<32) | (uint32_t)__builtin_amdgcn_readlane(bl, 16);
      unsigned long long k2 = (((unsigned long long)(uint32_t)__builtin_amdgcn_readlane(bh, 32))<<32) | (uint32_t)__builtin_amdgcn_readlane(bl, 32);
      unsigned long long k3 = (((unsigned long long)(uint32_t)__builtin_amdgcn_readlane(bh, 48))<<32) | (uint32_t)__builtin_amdgcn_readlane(bl, 48);
      unsigned long long kw = u64max(u64max(k0,k1), u64max(k2,k3));
      if (lane==0) sm.f.warr[t&1][wid] = __longlong_as_double((long long)kw);
      __syncthreads();
      double w0 = sm.f.warr[t&1][0], w1_ = sm.f.warr[t&1][1], w2_ = sm.f.warr[t&1][2], w3 = sm.f.warr[t&1][3];
      double f = fmax(fmax(w0,w1_), fmax(w2_,w3));
      int n = (int)(~(uint32_t)__double_as_longlong(f));
      float4 cc = sm.f.lc[n];
      cx = cc.x; cy = cc.y; cz = cc.z;
      if (tid==0) sm.f.sel[t]=n;
    }
    __syncthreads();
    for (int s = tid; s < NS; s += 256){
      int n = sm.f.sel[s];
      float4 cc = sm.f.lc[n];
      float* np_ = nxyz + ((size_t)b*NS + s)*3;
      np_[0]=cc.x; np_[1]=cc.y; np_[2]=cc.z;
      float* ob = out0 + (size_t)b*3*NS + s;
      ob[0]=cc.x; ob[NS]=cc.y; ob[2*NS]=cc.z;
    }
  } else if (blk < 528){
    // ---- transpose (B,64,N) fp32 -> (B,N,64) bf16 ----
    const int t2 = blk - 16;
    const int b = t2 >> 5;
    const int n0 = (t2 & 31) * 64;
    const int lane = tid & 63;
    const int row4 = tid >> 6;
    const float* src = pts + (size_t)b*64*NPT;
    #pragma unroll
    for (int r=0; r<16; r++){
      int cc = r*4 + row4;
      sm.tile[cc][lane] = src[(size_t)cc*NPT + n0 + lane];
    }
    __syncthreads();
    ushort* dst = pts_tb + ((size_t)b*NPT + n0)*64;
    #pragma unroll
    for (int r=0; r<16; r++){
      int nn = r*4 + row4;
      dst[(size_t)nn*64 + lane] = f2bf(sm.tile[lane][nn]);
    }
  } else {
    // ---- wcvt + zero stats ----
    for (int i = tid; i < 4096; i += 256) w1b[i] = f2bf(w1[i]);
    for (int i = tid; i < 8192; i += 256) w2b[i] = f2bf(w2[i]);
    for (int i = tid; i < 1536; i += 256) st[i] = 0.f;
  }
}

// ---------------- ball query ----------------
__global__ __launch_bounds__(256) void ballq_kernel(const float* __restrict__ xyz,
                                                    const float* __restrict__ nxyz,
                                                    int* __restrict__ gidx)
{
  const int g = blockIdx.x*4 + (threadIdx.x>>6);
  const int lane = threadIdx.x & 63;
  const int b = g >> 9;
  const float* xb = xyz + (size_t)b*3*NPT;
  const float* c = nxyz + (size_t)g*3;
  const float cx = c[0], cy = c[1], cz = c[2];
  const float r2 = 0.2f*0.2f;
  int cnt = 0; int first = 0;
  int* out = gidx + (size_t)g*NK;
  for (int ch=0; ch<NPT/64 && cnt<NK; ch++){
    int n = ch*64 + lane;
    float dx = __fsub_rn(cx, xb[n]);
    float dy = __fsub_rn(cy, xb[NPT+n]);
    float dz = __fsub_rn(cz, xb[2*NPT+n]);
    float d  = __fadd_rn(__fadd_rn(__fmul_rn(dx,dx),__fmul_rn(dy,dy)),__fmul_rn(dz,dz));
    bool in = (d <= r2);
    unsigned long long mask = __ballot(in);
    if (mask){
      if (cnt==0) first = ch*64 + (__ffsll((unsigned long long)mask)-1);
      if (in){
        int pos = cnt + __popcll(mask & ((1ull<<lane)-1ull));
        if (pos < NK) out[pos] = n;
      }
      cnt += __popcll(mask);
    }
  }
  if (cnt < NK && lane >= cnt && lane < NK) out[lane] = first;
}

// ---------------- conv1: gather + 67->64, pm-bf16 out ----------------
__global__ __launch_bounds__(256) void conv1_kernel(const float* __restrict__ xyz,
    const ushort* __restrict__ pts_tb, const int* __restrict__ gidx,
    const float* __restrict__ nxyz, const float* __restrict__ Wt,
    const float* __restrict__ bias, ushort* __restrict__ y1)
{
  const int p = blockIdx.x*256 + threadIdx.x;
  const int bs = p >> 5;
  const int b = p >> 14;
  const int n = gidx[p];
  float x[C_IN];
  {
    const float* xb = xyz + (size_t)b*3*NPT;
    const float* cc = nxyz + (size_t)bs*3;
    x[0] = xb[n]        - cc[0];
    x[1] = xb[NPT+n]    - cc[1];
    x[2] = xb[2*NPT+n]  - cc[2];
    const ushort* pr = pts_tb + ((size_t)b*NPT + n)*64;
    #pragma unroll
    for (int q=0;q<8;q++){
      short8 v = *(const short8*)(pr + q*8);
      #pragma unroll
      for (int j=0;j<8;j++) x[3+8*q+j] = bf2f((ushort)v[j]);
    }
  }
  ushort* yr = y1 + (size_t)p*64;
  #pragma unroll 1
  for (int o=0;o<64;o+=8){
    float a[8];
    #pragma unroll
    for (int k=0;k<8;k++) a[k] = bias[o+k];
    #pragma unroll
    for (int c=0;c<C_IN;c++){
      float xv = x[c];
      #pragma unroll
      for (int k=0;k<8;k++) a[k] = fmaf(Wt[(o+k)*C_IN+c], xv, a[k]);
    }
    short8 sv;
    #pragma unroll
    for (int k=0;k<8;k++) sv[k] = (short)f2bf(a[k]);
    *(short8*)(yr + o) = sv;
  }
}

// ---------------- stats over 64-ch pm-bf16: 256 blocks, replicated atomic sums ----------------
__global__ __launch_bounds__(256) void stats64_kernel(const ushort* __restrict__ y,
                                                      float* __restrict__ stbase)
{
  const int wid = threadIdx.x>>6, lane = threadIdx.x&63;
  const int oct = lane & 7, pr = lane >> 3;
  const int p0 = blockIdx.x*1024 + wid*256;
  float s[8], s2[8];
  #pragma unroll
  for (int j=0;j<8;j++){ s[j]=0.f; s2[j]=0.f; }
  for (int it=0; it<32; it++){
    int p = p0 + it*8 + pr;
    short8 v = *(const short8*)(y + (size_t)p*64 + oct*8);
    #pragma unroll
    for (int j=0;j<8;j++){
      float f = bf2f((ushort)v[j]);
      s[j] += f; s2[j] = fmaf(f,f,s2[j]);
    }
  }
  #pragma unroll
  for (int off=8; off<64; off<<=1){
    #pragma unroll
    for (int j=0;j<8;j++){ s[j] += __shfl_xor(s[j],off,64); s2[j] += __shfl_xor(s2[j],off,64); }
  }
  __shared__ float sd[4][128];
  if (pr==0){
    #pragma unroll
    for (int j=0;j<8;j++){ sd[wid][oct*8+j] = s[j]; sd[wid][64+oct*8+j] = s2[j]; }
  }
  __syncthreads();
  int t = threadIdx.x;
  if (t < 128){
    float v = sd[0][t]+sd[1][t]+sd[2][t]+sd[3][t];
    int rep = blockIdx.x & 1;
    float* dst = (t<64) ? (stbase + rep*64 + t) : (stbase + 128 + rep*64 + (t-64));
    atomicAdd(dst, v);
  }
}

// ---------------- conv2 MFMA: 64->64, affine computed in-block ----------------
__global__ __launch_bounds__(256) void conv2_mfma(const ushort* __restrict__ yin,
    const float* __restrict__ st, const float* __restrict__ g0, const float* __restrict__ bt0,
    const ushort* __restrict__ Wb, const float* __restrict__ bias,
    ushort* __restrict__ yout)
{
  __shared__ float aAl[64], aBl[64];
  const int tid = threadIdx.x;
  if (tid < 64){
    float s = st[tid] + st[64+tid];
    float qv = st[128+tid] + st[192+tid];
    float mean = s * (1.f/PTOT);
    float var  = qv * (1.f/PTOT) - mean*mean;
    float a = g0[tid] * rsqrtf(var + EPSV);
    aAl[tid] = a;
    aBl[tid] = fmaf(-mean, a, bt0[tid]);
  }
  __syncthreads();
  const int wid = tid>>6, lane = tid&63;
  const int q = lane>>4, nn = lane&15;
  const int p0 = (blockIdx.x*4 + wid) * 32;
  float a_[2][8], b_[2][8];
  #pragma unroll
  for (int kh=0;kh<2;kh++)
    #pragma unroll
    for (int j=0;j<8;j++){
      a_[kh][j] = aAl[kh*32 + q*8 + j];
      b_[kh][j] = aBl[kh*32 + q*8 + j];
    }
  short8 Af[4][2];
  #pragma unroll
  for (int mt=0;mt<4;mt++)
    #pragma unroll
    for (int kh=0;kh<2;kh++)
      Af[mt][kh] = *(const short8*)(Wb + (mt*16 + nn)*64 + kh*32 + q*8);
  float bias_[4][4];
  #pragma unroll
  for (int mt=0;mt<4;mt++)
    #pragma unroll
    for (int r=0;r<4;r++) bias_[mt][r] = bias[mt*16 + q*4 + r];
  floatx4 z = {0.f,0.f,0.f,0.f};
  floatx4 acc[4][2];
  #pragma unroll
  for (int mt=0;mt<4;mt++){ acc[mt][0]=z; acc[mt][1]=z; }
  #pragma unroll
  for (int nt=0;nt<2;nt++){
    #pragma unroll
    for (int kh=0;kh<2;kh++){
      short8 raw = *(const short8*)(yin + (size_t)(p0 + nt*16 + nn)*64 + kh*32 + q*8);
      short8 bf;
      #pragma unroll
      for (int j=0;j<8;j++){
        float f = bf2f((ushort)raw[j]);
        f = fmaxf(fmaf(f, a_[kh][j], b_[kh][j]), 0.f);
        bf[j] = (short)f2bf(f);
      }
      #pragma unroll
      for (int mt=0;mt<4;mt++)
        acc[mt][nt] = __builtin_amdgcn_mfma_f32_16x16x32_bf16(Af[mt][kh], bf, acc[mt][nt], 0,0,0);
    }
  }
  #pragma unroll
  for (int nt=0;nt<2;nt++){
    int p = p0 + nt*16 + nn;
    #pragma unroll
    for (int mt=0;mt<4;mt++){
      float v0 = acc[mt][nt][0] + bias_[mt][0];
      float v1 = acc[mt][nt][1] + bias_[mt][1];
      float v2 = acc[mt][nt][2] + bias_[mt][2];
      float v3 = acc[mt][nt][3] + bias_[mt][3];
      uint2 w;
      w.x = (uint32_t)f2bf(v0) | ((uint32_t)f2bf(v1)<<16);
      w.y = (uint32_t)f2bf(v2) | ((uint32_t)f2bf(v3)<<16);
      *(uint2*)(yout + (size_t)p*64 + mt*16 + q*4) = w;
    }
  }
}

// ---------------- conv3 MFMA: 64->128, affine in-block ----------------
__global__ __launch_bounds__(256) void conv3_mfma(const ushort* __restrict__ yin,
    const float* __restrict__ st, const float* __restrict__ g1, const float* __restrict__ bt1,
    const ushort* __restrict__ Wb, const float* __restrict__ bias,
    ushort* __restrict__ yout)
{
  __shared__ float aAl[64], aBl[64];
  const int tid = threadIdx.x;
  if (tid < 64){
    float s = st[256+tid] + st[320+tid];
    float qv = st[384+tid] + st[448+tid];
    float mean = s * (1.f/PTOT);
    float var  = qv * (1.f/PTOT) - mean*mean;
    float a = g1[tid] * rsqrtf(var + EPSV);
    aAl[tid] = a;
    aBl[tid] = fmaf(-mean, a, bt1[tid]);
  }
  __syncthreads();
  const int wid = tid>>6, lane = tid&63;
  const int q = lane>>4, nn = lane&15;
  const int p0 = (blockIdx.x*4 + wid) * 16;
  float a_[2][8], b_[2][8];
  #pragma unroll
  for (int kh=0;kh<2;kh++)
    #pragma unroll
    for (int j=0;j<8;j++){
      a_[kh][j] = aAl[kh*32 + q*8 + j];
      b_[kh][j] = aBl[kh*32 + q*8 + j];
    }
  short8 bfr[2];
  #pragma unroll
  for (int kh=0;kh<2;kh++){
    short8 raw = *(const short8*)(yin + (size_t)(p0 + nn)*64 + kh*32 + q*8);
    short8 bf;
    #pragma unroll
    for (int j=0;j<8;j++){
      float f = bf2f((ushort)raw[j]);
      f = fmaxf(fmaf(f, a_[kh][j], b_[kh][j]), 0.f);
      bf[j] = (short)f2bf(f);
    }
    bfr[kh] = bf;
  }
  #pragma unroll 1
  for (int mh=0;mh<2;mh++){
    floatx4 z = {0.f,0.f,0.f,0.f};
    floatx4 acc[4];
    short8 Af[4][2];
    #pragma unroll
    for (int mt=0;mt<4;mt++){
      acc[mt]=z;
      #pragma unroll
      for (int kh=0;kh<2;kh++)
        Af[mt][kh] = *(const short8*)(Wb + ((mh*4+mt)*16 + nn)*64 + kh*32 + q*8);
    }
    #pragma unroll
    for (int kh=0;kh<2;kh++)
      #pragma unroll
      for (int mt=0;mt<4;mt++)
        acc[mt] = __builtin_amdgcn_mfma_f32_16x16x32_bf16(Af[mt][kh], bfr[kh], acc[mt], 0,0,0);
    int p = p0 + nn;
    #pragma unroll
    for (int mt=0;mt<4;mt++){
      int m0 = (mh*4+mt)*16;
      float v0 = acc[mt][0] + bias[m0 + q*4 + 0];
      float v1 = acc[mt][1] + bias[m0 + q*4 + 1];
      float v2 = acc[mt][2] + bias[m0 + q*4 + 2];
      float v3 = acc[mt][3] + bias[m0 + q*4 + 3];
      uint2 w;
      w.x = (uint32_t)f2bf(v0) | ((uint32_t)f2bf(v1)<<16);
      w.y = (uint32_t)f2bf(v2) | ((uint32_t)f2bf(v3)<<16);
      *(uint2*)(yout + (size_t)p*128 + m0 + q*4) = w;
    }
  }
}

// ---------------- stats + group-max over 128-ch pm-bf16 y3: 512 blocks ----------------
__global__ __launch_bounds__(256) void statsmax_kernel(const ushort* __restrict__ y,
    float* __restrict__ st, ushort* __restrict__ rawmax)
{
  const int wid = threadIdx.x>>6, lane = threadIdx.x&63;
  const int oct = lane & 15, pr = lane >> 4;
  const int g0 = (blockIdx.x*4 + wid) * 4;
  float s[8], s2[8];
  #pragma unroll
  for (int j=0;j<8;j++){ s[j]=0.f; s2[j]=0.f; }
  for (int gi=0; gi<4; gi++){
    int g = g0 + gi;
    float mx[8];
    #pragma unroll
    for (int j=0;j<8;j++) mx[j] = -1e30f;
    for (int it=0; it<8; it++){
      int p = g*32 + it*4 + pr;
      short8 v = *(const short8*)(y + (size_t)p*128 + oct*8);
      #pragma unroll
      for (int j=0;j<8;j++){
        float f = bf2f((ushort)v[j]);
        s[j] += f; s2[j] = fmaf(f,f,s2[j]);
        mx[j] = fmaxf(mx[j], f);
      }
    }
    #pragma unroll
    for (int j=0;j<8;j++){
      mx[j] = fmaxf(mx[j], __shfl_xor(mx[j],16,64));
      mx[j] = fmaxf(mx[j], __shfl_xor(mx[j],32,64));
    }
    if (pr==0){
      short8 sv;
      #pragma unroll
      for (int j=0;j<8;j++) sv[j] = (short)f2bf(mx[j]);
      *(short8*)(rawmax + (size_t)g*128 + oct*8) = sv;
    }
  }
  #pragma unroll
  for (int j=0;j<8;j++){
    s[j]  += __shfl_xor(s[j],16,64);  s[j]  += __shfl_xor(s[j],32,64);
    s2[j] += __shfl_xor(s2[j],16,64); s2[j] += __shfl_xor(s2[j],32,64);
  }
  __shared__ float sd[4][256];
  if (pr==0){
    #pragma unroll
    for (int j=0;j<8;j++){ sd[wid][oct*8+j] = s[j]; sd[wid][128+oct*8+j] = s2[j]; }
  }
  __syncthreads();
  int t = threadIdx.x;
  float v = sd[0][t]+sd[1][t]+sd[2][t]+sd[3][t];
  int rep = blockIdx.x & 3;
  float* dst = (t<128) ? (st + 512 + rep*128 + t) : (st + 1024 + rep*128 + (t-128));
  atomicAdd(dst, v);
}

// ---------------- finalize: tiled transpose + affine+relu ----------------
__global__ __launch_bounds__(256) void finalize_kernel(const ushort* __restrict__ rawmax,
    const float* __restrict__ st, const float* __restrict__ g2, const float* __restrict__ bt2,
    float* __restrict__ out)
{
  __shared__ float tile[64][65];
  __shared__ float aAl[128], aBl[128];
  const int tid = threadIdx.x;
  if (tid < 128){
    float s = st[512+tid] + st[640+tid] + st[768+tid] + st[896+tid];
    float qv = st[1024+tid] + st[1152+tid] + st[1280+tid] + st[1408+tid];
    float mean = s * (1.f/PTOT);
    float var  = qv * (1.f/PTOT) - mean*mean;
    float a = g2[tid] * rsqrtf(var + EPSV);
    aAl[tid] = a;
    aBl[tid] = fmaf(-mean, a, bt2[tid]);
  }
  __syncthreads();
  const int b  = blockIdx.x >> 4;
  const int ct = (blockIdx.x >> 3) & 1;
  const int stt = blockIdx.x & 7;
  const int c0 = ct*64, s0 = stt*64;
  const int lane = tid & 63, wid = tid >> 6;
  #pragma unroll
  for (int r=0;r<16;r++){
    int sl = r*4 + wid;
    tile[sl][lane] = bf2f(rawmax[((size_t)(b*512 + s0 + sl))*128 + c0 + lane]);
  }
  __syncthreads();
  #pragma unroll
  for (int r=0;r<16;r++){
    int cl = r*4 + wid;
    float a = aAl[c0+cl], bb = aBl[c0+cl];
    out[((size_t)(b*128 + c0 + cl))*512 + s0 + lane] = fmaxf(fmaf(tile[lane][cl], a, bb), 0.f);
  }
}

extern "C" void kernel_launch(void* const* d_in, const int* in_sizes, int n_in,
                              void* d_out, int out_size, void* d_ws, size_t ws_size,
                              hipStream_t stream) {
  const float* xyz = (const float*)d_in[0];
  const float* pts = (const float*)d_in[1];
  const float* w0  = (const float*)d_in[2];
  const float* b0  = (const float*)d_in[3];
  const float* g0  = (const float*)d_in[4];
  const float* bt0 = (const float*)d_in[5];
  const float* w1  = (const float*)d_in[6];
  const float* b1  = (const float*)d_in[7];
  const float* g1  = (const float*)d_in[8];
  const float* bt1 = (const float*)d_in[9];
  const float* w2  = (const float*)d_in[10];
  const float* b2  = (const float*)d_in[11];
  const float* g2  = (const float*)d_in[12];
  const float* bt2 = (const float*)d_in[13];
  float* out = (float*)d_out;
  float* ws  = (float*)d_ws;

  float* nxyz   = ws + WS_NEWXYZ;
  int*   gidx   = (int*)(ws + WS_GIDX);
  float* st     = ws + WS_ST;
  ushort* w1b = (ushort*)(ws + WS_W1BF);
  ushort* w2b = (ushort*)(ws + WS_W2BF);
  ushort* rawmax = (ushort*)(ws + WS_RAWMAX);
  ushort* pts_tb = (ushort*)(ws + WS_PTS_TB);
  ushort* y1 = (ushort*)(ws + WS_Y1);
  ushort* y2 = (ushort*)(ws + WS_Y2);
  ushort* y3 = (ushort*)(ws + WS_Y3);

  prep_kernel<<<529,256,0,stream>>>(xyz, nxyz, out, pts, pts_tb, w1, w2, w1b, w2b, st);
  ballq_kernel<<<2048,256,0,stream>>>(xyz, nxyz, gidx);
  conv1_kernel<<<PTOT/256,256,0,stream>>>(xyz, pts_tb, gidx, nxyz, w0, b0, y1);
  stats64_kernel<<<256,256,0,stream>>>(y1, st);
  conv2_mfma<<<2048,256,0,stream>>>(y1, st, g0, bt0, w1b, b1, y2);
  stats64_kernel<<<256,256,0,stream>>>(y2, st + 256);
  conv3_mfma<<<4096,256,0,stream>>>(y2, st, g1, bt1, w2b, b2, y3);
  statsmax_kernel<<<512,256,0,stream>>>(y3, st, rawmax);
  finalize_kernel<<<256,256,0,stream>>>(rawmax, st, g2, bt2, out + NB*3*NS);
}